// Round 2
// baseline (1785.515 us; speedup 1.0000x reference)
//
#include <hip/hip_runtime.h>
#include <hip/hip_bf16.h>
#include <cstdint>
#include <cstddef>

#define F_IN 767
#define HD   16

// ======================= counting-sort of edges by col =======================

__global__ void k_hist(const int* __restrict__ col, int* __restrict__ cnt, int E) {
  int e = blockIdx.x * 256 + threadIdx.x;
  if (e < E) atomicAdd(&cnt[col[e]], 1);
}

// block scan: 256 threads x 4 items = 1024 items/block.
__global__ void k_scan1(const int* __restrict__ cnt, int* __restrict__ off,
                        int* __restrict__ bsum, int N) {
  __shared__ int lds[256];
  int t = threadIdx.x;
  int base = blockIdx.x * 1024 + t * 4;
  int4 v = make_int4(0, 0, 0, 0);
  if (base + 3 < N) {
    v = *(const int4*)&cnt[base];
  } else {
    if (base + 0 < N) v.x = cnt[base + 0];
    if (base + 1 < N) v.y = cnt[base + 1];
    if (base + 2 < N) v.z = cnt[base + 2];
    if (base + 3 < N) v.w = cnt[base + 3];
  }
  int s = v.x + v.y + v.z + v.w;
  lds[t] = s;
  __syncthreads();
  for (int d = 1; d < 256; d <<= 1) {
    int add = (t >= d) ? lds[t - d] : 0;
    __syncthreads();
    lds[t] += add;
    __syncthreads();
  }
  int excl = lds[t] - s;
  if (t == 255) bsum[blockIdx.x] = lds[255];
  int run = excl;
  if (base + 0 < N) off[base + 0] = run; run += v.x;
  if (base + 1 < N) off[base + 1] = run; run += v.y;
  if (base + 2 < N) off[base + 2] = run; run += v.z;
  if (base + 3 < N) off[base + 3] = run;
}

// single block: exclusive scan of block sums in place (nb <= 256)
__global__ void k_scan2(int* __restrict__ bsum, int nb) {
  __shared__ int lds[256];
  int t = threadIdx.x;
  int s = (t < nb) ? bsum[t] : 0;
  lds[t] = s;
  __syncthreads();
  for (int d = 1; d < 256; d <<= 1) {
    int add = (t >= d) ? lds[t - d] : 0;
    __syncthreads();
    lds[t] += add;
    __syncthreads();
  }
  if (t < nb) bsum[t] = lds[t] - s;
}

// finalize offsets, copy to cursor, compute dinv
__global__ void k_scan3(const int* __restrict__ cnt, int* __restrict__ off,
                        int* __restrict__ cur, float* __restrict__ dinv,
                        const int* __restrict__ bsum, int N) {
  int i = blockIdx.x * 256 + threadIdx.x;
  if (i < N) {
    int o = off[i] + bsum[i >> 10];
    off[i] = o;
    cur[i] = o;
    int c = cnt[i];
    dinv[i] = (c > 0) ? rsqrtf((float)c) : 0.f;
  }
}

__global__ void k_build(const int* __restrict__ row, const int* __restrict__ col,
                        int* __restrict__ cur, int* __restrict__ srow, int E) {
  int e = blockIdx.x * 256 + threadIdx.x;
  if (e < E) {
    int c = col[e];
    int p = atomicAdd(&cur[c], 1);
    srow[p] = row[e];
  }
}

// ======================= weight pack: f32 [wi | wr] -> f32 Wc[K][2H] =======================
__global__ void k_pack(const float* __restrict__ wi, const float* __restrict__ wr,
                       float* __restrict__ Wc, int K, int H) {
  int i = blockIdx.x * 256 + threadIdx.x;
  int tot = K * 2 * H;
  if (i < tot) {
    int k = i / (2 * H), c = i % (2 * H);
    Wc[i] = (c < H) ? wi[k * H + c] : wr[k * H + (c - H)];
  }
}

// ======================= GEMM1: x[N,767](f32) @ Wc[767,32](f32) -> T[N,32](f32) =======================
// Split-K=4, 256-row tile, 128 threads (2 waves), 8x8 register tile per thread.
// xs is XOR-swizzled at float4-quad granularity so staging writes and compute
// reads are both 2-way-per-bank (free). Partials combined via f32 atomicAdd.
#define G1_KC  16     // k per chunk
#define G1_M   256    // rows per block
#define G1_SK  4      // k-splits
#define G1_KR  192    // k-range per split (4*192 >= 767)

__global__ __launch_bounds__(128, 3) void k_gemm1(const float* __restrict__ x,
                                                  const float* __restrict__ Wc,
                                                  float* __restrict__ T, int N) {
  __shared__ __align__(16) float xs[G1_KC * G1_M];   // [kk][(quad ^ (kk&7))*4 + j]
  __shared__ __align__(16) float ws[G1_KC * 32];     // [kk][col]
  int t = threadIdx.x;
  int tn = t & 3;          // colgroup -> cols tn*8..tn*8+7
  int tm = t >> 2;         // 0..31 -> row quads {tm, tm+32} = rows tm*4+j, 128+tm*4+j
  int rowBase = blockIdx.x * G1_M;
  int k0 = blockIdx.y * G1_KR;
  int kend = min(k0 + G1_KR, F_IN);

  int kl = t & 15;         // staging: k lane
  int tr = t >> 4;         // staging: row offset 0..7

  float acc[8][8];
  #pragma unroll
  for (int m = 0; m < 8; ++m)
    #pragma unroll
    for (int c = 0; c < 8; ++c) acc[m][c] = 0.f;

  for (int kc = k0; kc < kend; kc += G1_KC) {
    // ---- stage xs: 256 rows x 16 k. Per instruction a wave reads 4 rows x 16
    // consecutive dwords (coalesced). Write swizzle: quad ^= (k&7).
    {
      int kg = kc + kl;
      bool kval = (kg < kend);
      const float* xp = x + (size_t)(rowBase + tr) * F_IN + kg;
      int sxw = kl & 7;
      #pragma unroll
      for (int i = 0; i < 32; ++i) {
        int r = i * 8 + tr;                 // 0..255
        int gr = rowBase + r;
        float v = 0.f;
        if (kval && gr < N) v = xp[(size_t)(i * 8) * F_IN];
        int q = r >> 2, j = r & 3;
        xs[kl * G1_M + ((q ^ sxw) << 2) + j] = v;
      }
      // ---- stage ws: 16 k x 32 cols
      #pragma unroll
      for (int i = 0; i < 4; ++i) {
        int idx = i * 128 + t;              // 0..511
        int wk = idx >> 5, wc = idx & 31;
        int kg2 = kc + wk;
        ws[idx] = (kg2 < kend) ? Wc[(size_t)kg2 * 32 + wc] : 0.f;
      }
    }
    __syncthreads();
    #pragma unroll
    for (int kk = 0; kk < G1_KC; ++kk) {
      const float* xrow = &xs[kk * G1_M];
      const int s = kk & 7;
      float4 a0 = *(const float4*)&xrow[((tm ^ s) << 2)];            // rows tm*4..+3
      float4 a1 = *(const float4*)&xrow[(((tm ^ s) + 32) << 2)];     // rows 128+tm*4..+3
      float4 b0 = *(const float4*)&ws[kk * 32 + tn * 8];
      float4 b1 = *(const float4*)&ws[kk * 32 + tn * 8 + 4];
      float am[8] = {a0.x, a0.y, a0.z, a0.w, a1.x, a1.y, a1.z, a1.w};
      float bn[8] = {b0.x, b0.y, b0.z, b0.w, b1.x, b1.y, b1.z, b1.w};
      #pragma unroll
      for (int m = 0; m < 8; ++m)
        #pragma unroll
        for (int c = 0; c < 8; ++c) acc[m][c] += am[m] * bn[c];
    }
    __syncthreads();
  }

  // ---- writeback: f32 atomics combine the 4 k-splits (T pre-zeroed)
  #pragma unroll
  for (int half = 0; half < 2; ++half) {
    #pragma unroll
    for (int j = 0; j < 4; ++j) {
      int r = rowBase + half * 128 + tm * 4 + j;
      if (r < N) {
        float* tp = &T[(size_t)r * 32 + tn * 8];
        #pragma unroll
        for (int c = 0; c < 8; ++c) atomicAdd(&tp[c], acc[half * 4 + j][c]);
      }
    }
  }
}

// ======================= small GEMM: h[N,16](f32) @ W[16,P](f32) -> T[N,P](f32) =======================
__global__ void k_gemm_small(const float* __restrict__ h, const float* __restrict__ W,
                             float* __restrict__ T, int N, int P) {
  int idx = blockIdx.x * 256 + threadIdx.x;
  int n = idx >> 5, c = idx & 31;
  if (n < N && c < P) {
    float acc = 0.f;
    #pragma unroll
    for (int k = 0; k < HD; ++k) acc += h[(size_t)n * HD + k] * W[k * P + c];
    T[(size_t)n * P + c] = acc;
  }
}

// ======================= gather + relu epilogue (layers 1,2) =======================
__global__ void k_gather_relu(const float* __restrict__ T, const int* __restrict__ off,
                              const int* __restrict__ cnt, const int* __restrict__ srow,
                              const float* __restrict__ dinv, const float* __restrict__ bias,
                              float* __restrict__ hout, int N) {
  int t = threadIdx.x;
  int j = t & 15, ln = t >> 4;
  int n = blockIdx.x * 16 + ln;
  if (n >= N) return;
  int s = off[n], c = cnt[n];
  float acc = 0.f;
  for (int p = s; p < s + c; ++p) {
    int r = srow[p];
    acc += dinv[r] * T[(size_t)r * 32 + j];
  }
  float v = dinv[n] * acc + T[(size_t)n * 32 + 16 + j] + bias[j];
  hout[(size_t)n * HD + j] = fmaxf(v, 0.f);
}

// ======================= gather + relu + log_softmax (layer 3, C=10, pitch 20), f32 out ===========
// ARMAConv applies relu INTERNALLY in every conv, including conv3: logits = relu(agg + h@w_root + b).
__global__ void k_gather_lsm(const float* __restrict__ T, const int* __restrict__ off,
                             const int* __restrict__ cnt, const int* __restrict__ srow,
                             const float* __restrict__ dinv, const float* __restrict__ b3,
                             float* __restrict__ out, int N) {
  int t = threadIdx.x;
  int j = t & 15, ln = t >> 4;
  int n = blockIdx.x * 16 + ln;
  bool act = (n < N) && (j < 10);
  float v = -1e30f;
  if (act) {
    int s = off[n], c = cnt[n];
    float acc = 0.f;
    for (int p = s; p < s + c; ++p) {
      int r = srow[p];
      acc += dinv[r] * T[(size_t)r * 20 + j];
    }
    v = dinv[n] * acc + T[(size_t)n * 20 + 10 + j] + b3[j];
    v = fmaxf(v, 0.f);   // ARMAConv internal relu on conv3 output
  }
  float m = v;
  #pragma unroll
  for (int mask = 8; mask >= 1; mask >>= 1) m = fmaxf(m, __shfl_xor(m, mask, 16));
  float e = act ? __expf(v - m) : 0.f;
  float sum = e;
  #pragma unroll
  for (int mask = 8; mask >= 1; mask >>= 1) sum += __shfl_xor(sum, mask, 16);
  if (act) out[(size_t)n * 10 + j] = (v - m) - __logf(sum);
}

// ======================= launch =======================
extern "C" void kernel_launch(void* const* d_in, const int* in_sizes, int n_in,
                              void* d_out, int out_size, void* d_ws, size_t ws_size,
                              hipStream_t stream) {
  const float* x    = (const float*)d_in[0];
  const int* eidx   = (const int*)d_in[1];
  const float* w1i  = (const float*)d_in[2];
  const float* w1r  = (const float*)d_in[3];
  const float* b1   = (const float*)d_in[4];
  const float* w2i  = (const float*)d_in[5];
  const float* w2r  = (const float*)d_in[6];
  const float* b2   = (const float*)d_in[7];
  const float* w3i  = (const float*)d_in[8];
  const float* w3r  = (const float*)d_in[9];
  const float* b3   = (const float*)d_in[10];
  float* out = (float*)d_out;

  const int N = in_sizes[0] / F_IN;     // 100000
  const int E = in_sizes[1] / 2;        // 3200000
  const int* row = eidx;
  const int* col = eidx + E;

  // workspace carve-up (256B aligned)
  char* p = (char*)d_ws;
  auto alloc = [&](size_t bytes) { void* r = (void*)p; p += (bytes + 255) & ~(size_t)255; return r; };
  int*   cnt  = (int*)alloc((size_t)N * 4);
  int*   off  = (int*)alloc((size_t)N * 4);
  int*   cur  = (int*)alloc((size_t)N * 4);
  float* dinv = (float*)alloc((size_t)N * 4);
  int*   bsum = (int*)alloc(1024);
  float* Wc   = (float*)alloc((size_t)F_IN * 32 * 4);
  float* W2c  = (float*)alloc((size_t)HD * 32 * 4);
  float* W3c  = (float*)alloc((size_t)HD * 20 * 4);
  int*   srow = (int*)alloc((size_t)E * 4);
  float* T    = (float*)alloc((size_t)N * 32 * 4);
  float* h    = (float*)alloc((size_t)N * HD * 4);

  const int nbE = (E + 255) / 256;
  const int nbScan = (N + 1023) / 1024;     // 98

  // edge sort (counting sort by col) + dinv
  hipMemsetAsync(cnt, 0, (size_t)N * 4, stream);
  k_hist <<<nbE, 256, 0, stream>>>(col, cnt, E);
  k_scan1<<<nbScan, 256, 0, stream>>>(cnt, off, bsum, N);
  k_scan2<<<1, 256, 0, stream>>>(bsum, nbScan);
  k_scan3<<<(N + 255) / 256, 256, 0, stream>>>(cnt, off, cur, dinv, bsum, N);
  k_build<<<nbE, 256, 0, stream>>>(row, col, cur, srow, E);

  // pack weights
  k_pack<<<(F_IN * 32 + 255) / 256, 256, 0, stream>>>(w1i, w1r, Wc, F_IN, 16);
  k_pack<<<(HD * 32 + 255) / 256, 256, 0, stream>>>(w2i, w2r, W2c, HD, 16);
  k_pack<<<(HD * 20 + 255) / 256, 256, 0, stream>>>(w3i, w3r, W3c, HD, 10);

  // layer 1 (split-K partials combined via atomics -> zero T first)
  hipMemsetAsync(T, 0, (size_t)N * 32 * 4, stream);
  k_gemm1<<<dim3((N + G1_M - 1) / G1_M, G1_SK), 128, 0, stream>>>(x, Wc, T, N);
  k_gather_relu<<<(N + 15) / 16, 256, 0, stream>>>(T, off, cnt, srow, dinv, b1, h, N);
  // layer 2
  k_gemm_small<<<(N * 32 + 255) / 256, 256, 0, stream>>>(h, W2c, T, N, 32);
  k_gather_relu<<<(N + 15) / 16, 256, 0, stream>>>(T, off, cnt, srow, dinv, b2, h, N);
  // layer 3 + internal relu + log_softmax
  k_gemm_small<<<(N * 32 + 255) / 256, 256, 0, stream>>>(h, W3c, T, N, 20);
  k_gather_lsm<<<(N + 15) / 16, 256, 0, stream>>>(T, off, cnt, srow, dinv, b3, out, N);
}

// Round 3
// 1241.084 us; speedup vs baseline: 1.4387x; 1.4387x over previous
//
#include <hip/hip_runtime.h>
#include <hip/hip_bf16.h>
#include <cstdint>
#include <cstddef>

#define F_IN 767
#define HD   16

// ======================= counting-sort of edges by col =======================

__global__ void k_hist(const int* __restrict__ col, int* __restrict__ cnt, int E) {
  int e = blockIdx.x * 256 + threadIdx.x;
  if (e < E) atomicAdd(&cnt[col[e]], 1);
}

// block scan: 256 threads x 4 items = 1024 items/block.
__global__ void k_scan1(const int* __restrict__ cnt, int* __restrict__ off,
                        int* __restrict__ bsum, int N) {
  __shared__ int lds[256];
  int t = threadIdx.x;
  int base = blockIdx.x * 1024 + t * 4;
  int4 v = make_int4(0, 0, 0, 0);
  if (base + 3 < N) {
    v = *(const int4*)&cnt[base];
  } else {
    if (base + 0 < N) v.x = cnt[base + 0];
    if (base + 1 < N) v.y = cnt[base + 1];
    if (base + 2 < N) v.z = cnt[base + 2];
    if (base + 3 < N) v.w = cnt[base + 3];
  }
  int s = v.x + v.y + v.z + v.w;
  lds[t] = s;
  __syncthreads();
  for (int d = 1; d < 256; d <<= 1) {
    int add = (t >= d) ? lds[t - d] : 0;
    __syncthreads();
    lds[t] += add;
    __syncthreads();
  }
  int excl = lds[t] - s;
  if (t == 255) bsum[blockIdx.x] = lds[255];
  int run = excl;
  if (base + 0 < N) off[base + 0] = run; run += v.x;
  if (base + 1 < N) off[base + 1] = run; run += v.y;
  if (base + 2 < N) off[base + 2] = run; run += v.z;
  if (base + 3 < N) off[base + 3] = run;
}

// single block: exclusive scan of block sums in place (nb <= 256)
__global__ void k_scan2(int* __restrict__ bsum, int nb) {
  __shared__ int lds[256];
  int t = threadIdx.x;
  int s = (t < nb) ? bsum[t] : 0;
  lds[t] = s;
  __syncthreads();
  for (int d = 1; d < 256; d <<= 1) {
    int add = (t >= d) ? lds[t - d] : 0;
    __syncthreads();
    lds[t] += add;
    __syncthreads();
  }
  if (t < nb) bsum[t] = lds[t] - s;
}

// finalize offsets, copy to cursor, compute dinv
__global__ void k_scan3(const int* __restrict__ cnt, int* __restrict__ off,
                        int* __restrict__ cur, float* __restrict__ dinv,
                        const int* __restrict__ bsum, int N) {
  int i = blockIdx.x * 256 + threadIdx.x;
  if (i < N) {
    int o = off[i] + bsum[i >> 10];
    off[i] = o;
    cur[i] = o;
    int c = cnt[i];
    dinv[i] = (c > 0) ? rsqrtf((float)c) : 0.f;
  }
}

__global__ void k_build(const int* __restrict__ row, const int* __restrict__ col,
                        int* __restrict__ cur, int* __restrict__ srow, int E) {
  int e = blockIdx.x * 256 + threadIdx.x;
  if (e < E) {
    int c = col[e];
    int p = atomicAdd(&cur[c], 1);
    srow[p] = row[e];
  }
}

// ======================= weight pack: f32 [wi | wr] -> f32 Wc[K][2H] =======================
__global__ void k_pack(const float* __restrict__ wi, const float* __restrict__ wr,
                       float* __restrict__ Wc, int K, int H) {
  int i = blockIdx.x * 256 + threadIdx.x;
  int tot = K * 2 * H;
  if (i < tot) {
    int k = i / (2 * H), c = i % (2 * H);
    Wc[i] = (c < H) ? wi[k * H + c] : wr[k * H + (c - H)];
  }
}

// ======================= GEMM1: x[N,767](f32) @ Wc[767,32](f32) -> T[N,32](f32) =======================
// M=64 rows/block (1563 blocks -> ~6 blocks/CU), 128 threads, 4x4 thread tile.
// Reg-staged double-buffered pipeline: issue chunk c+1 global loads, compute chunk c
// from LDS (hides HBM latency under ~1024 cyc of fmac), then ds_write c+1, barrier.
// xs is XOR-swizzled at float4-quad granularity: staging writes and compute reads
// are both <=2-way per bank. dinv[row] scale folded into the store of cols 0..15.
#define G1_KC  32     // k per chunk
#define G1_M   64     // rows per block

__global__ __launch_bounds__(128) void k_gemm1(const float* __restrict__ x,
                                               const float* __restrict__ Wc,
                                               const float* __restrict__ dinv,
                                               float* __restrict__ T, int N) {
  __shared__ __align__(16) float xs[2][G1_KC * G1_M];   // [buf][kk*64 + ((q^(kk&7))<<2)+j]
  __shared__ __align__(16) float ws[2][G1_KC * 32];     // [buf][kk*32 + col]
  int t = threadIdx.x;
  int tn = t & 7;          // col group -> cols tn*4..tn*4+3
  int tm = t >> 3;         // quad 0..15 -> rows tm*4..tm*4+3
  int rowBase = blockIdx.x * G1_M;

  int kl = t & 15;         // staging: k lane (16 consecutive k -> 64B coalesced)
  int rr = t >> 4;         // staging: row offset 0..7
  int sxw = kl & 7;        // swizzle for this k lane ((kh*16+kl)&7 == kl&7)

  float xv[16];            // stage regs: [i*2+kh], row=i*8+rr, k=kh*16+kl
  float wv[8];

  const int NC = (F_IN + G1_KC - 1) / G1_KC;   // 24

  float acc[4][4];
  #pragma unroll
  for (int m = 0; m < 4; ++m)
    #pragma unroll
    for (int c = 0; c < 4; ++c) acc[m][c] = 0.f;

  // ---- prologue: load + write chunk 0
  {
    const int kc = 0;
    #pragma unroll
    for (int kh = 0; kh < 2; ++kh) {
      int kg = kc + kh * 16 + kl;
      #pragma unroll
      for (int i = 0; i < 8; ++i) {
        int gr = rowBase + i * 8 + rr;
        float v = 0.f;
        if (gr < N) v = x[(size_t)gr * F_IN + kg];   // kg < 32 always valid
        xv[i * 2 + kh] = v;
      }
    }
    #pragma unroll
    for (int i = 0; i < 8; ++i) {
      int idx = i * 128 + t;
      int wk = idx >> 5, wc = idx & 31;
      wv[i] = Wc[(size_t)(kc + wk) * 32 + wc];
    }
    #pragma unroll
    for (int kh = 0; kh < 2; ++kh)
      #pragma unroll
      for (int i = 0; i < 8; ++i) {
        int r = i * 8 + rr;
        int q = r >> 2, j = r & 3;
        xs[0][(kh * 16 + kl) * G1_M + ((q ^ sxw) << 2) + j] = xv[i * 2 + kh];
      }
    #pragma unroll
    for (int i = 0; i < 8; ++i) ws[0][i * 128 + t] = wv[i];
  }
  __syncthreads();

  for (int c = 0; c < NC; ++c) {
    int b = c & 1;
    // ---- issue next chunk's global loads (latency hidden under compute)
    if (c + 1 < NC) {
      int kc = (c + 1) * G1_KC;
      #pragma unroll
      for (int kh = 0; kh < 2; ++kh) {
        int kg = kc + kh * 16 + kl;
        bool kval = (kg < F_IN);
        #pragma unroll
        for (int i = 0; i < 8; ++i) {
          int gr = rowBase + i * 8 + rr;
          float v = 0.f;
          if (kval && gr < N) v = x[(size_t)gr * F_IN + kg];
          xv[i * 2 + kh] = v;
        }
      }
      #pragma unroll
      for (int i = 0; i < 8; ++i) {
        int idx = i * 128 + t;
        int wk = idx >> 5, wc = idx & 31;
        int kg = kc + wk;
        wv[i] = (kg < F_IN) ? Wc[(size_t)kg * 32 + wc] : 0.f;
      }
    }
    // ---- compute chunk c from LDS buffer b
    const float* xb = &xs[b][0];
    const float* wb = &ws[b][0];
    #pragma unroll
    for (int kk = 0; kk < G1_KC; ++kk) {
      const int s = kk & 7;
      float4 a  = *(const float4*)&xb[kk * G1_M + ((tm ^ s) << 2)];
      float4 bv = *(const float4*)&wb[kk * 32 + tn * 4];
      float am[4] = {a.x, a.y, a.z, a.w};
      float bn[4] = {bv.x, bv.y, bv.z, bv.w};
      #pragma unroll
      for (int m = 0; m < 4; ++m)
        #pragma unroll
        for (int cc = 0; cc < 4; ++cc) acc[m][cc] += am[m] * bn[cc];
    }
    // ---- stage chunk c+1 into the other buffer
    if (c + 1 < NC) {
      __syncthreads();   // all waves done reading buf b^1 (chunk c-1)
      #pragma unroll
      for (int kh = 0; kh < 2; ++kh)
        #pragma unroll
        for (int i = 0; i < 8; ++i) {
          int r = i * 8 + rr;
          int q = r >> 2, j = r & 3;
          xs[b ^ 1][(kh * 16 + kl) * G1_M + ((q ^ sxw) << 2) + j] = xv[i * 2 + kh];
        }
      #pragma unroll
      for (int i = 0; i < 8; ++i) ws[b ^ 1][i * 128 + t] = wv[i];
      __syncthreads();   // writes visible before next compute
    }
  }

  // ---- epilogue: plain stores; fold dinv[row] into init cols (tn<4 <=> col<16)
  #pragma unroll
  for (int m = 0; m < 4; ++m) {
    int r = rowBase + tm * 4 + m;
    if (r < N) {
      float4 o = make_float4(acc[m][0], acc[m][1], acc[m][2], acc[m][3]);
      if (tn < 4) {
        float d = dinv[r];
        o.x *= d; o.y *= d; o.z *= d; o.w *= d;
      }
      *(float4*)&T[(size_t)r * 32 + tn * 4] = o;
    }
  }
}

// ======================= small GEMM: h[N,16](f32) @ W[16,P](f32) -> T[N,P](f32) =======================
// Cols c < SC (the "init" half) are pre-scaled by dinv[n] so the gather kernels
// don't need the per-edge dinv[r] random read.
__global__ void k_gemm_small(const float* __restrict__ h, const float* __restrict__ W,
                             const float* __restrict__ dinv,
                             float* __restrict__ T, int N, int P, int SC) {
  int idx = blockIdx.x * 256 + threadIdx.x;
  int n = idx >> 5, c = idx & 31;
  if (n < N && c < P) {
    float acc = 0.f;
    #pragma unroll
    for (int k = 0; k < HD; ++k) acc += h[(size_t)n * HD + k] * W[k * P + c];
    if (c < SC) acc *= dinv[n];
    T[(size_t)n * P + c] = acc;
  }
}

// ======================= gather + relu epilogue (layers 1,2) =======================
// T cols 0..15 already scaled by dinv[row] at the producer.
__global__ void k_gather_relu(const float* __restrict__ T, const int* __restrict__ off,
                              const int* __restrict__ cnt, const int* __restrict__ srow,
                              const float* __restrict__ dinv, const float* __restrict__ bias,
                              float* __restrict__ hout, int N) {
  int t = threadIdx.x;
  int j = t & 15, ln = t >> 4;
  int n = blockIdx.x * 16 + ln;
  if (n >= N) return;
  int s = off[n], c = cnt[n];
  float acc = 0.f;
  for (int p = s; p < s + c; ++p) {
    int r = srow[p];
    acc += T[(size_t)r * 32 + j];
  }
  float v = dinv[n] * acc + T[(size_t)n * 32 + 16 + j] + bias[j];
  hout[(size_t)n * HD + j] = fmaxf(v, 0.f);
}

// ======================= gather + relu + log_softmax (layer 3, C=10, pitch 20), f32 out ===========
// ARMAConv applies relu INTERNALLY in every conv, including conv3: logits = relu(agg + h@w_root + b).
__global__ void k_gather_lsm(const float* __restrict__ T, const int* __restrict__ off,
                             const int* __restrict__ cnt, const int* __restrict__ srow,
                             const float* __restrict__ dinv, const float* __restrict__ b3,
                             float* __restrict__ out, int N) {
  int t = threadIdx.x;
  int j = t & 15, ln = t >> 4;
  int n = blockIdx.x * 16 + ln;
  bool act = (n < N) && (j < 10);
  float v = -1e30f;
  if (act) {
    int s = off[n], c = cnt[n];
    float acc = 0.f;
    for (int p = s; p < s + c; ++p) {
      int r = srow[p];
      acc += T[(size_t)r * 20 + j];
    }
    v = dinv[n] * acc + T[(size_t)n * 20 + 10 + j] + b3[j];
    v = fmaxf(v, 0.f);   // ARMAConv internal relu on conv3 output
  }
  float m = v;
  #pragma unroll
  for (int mask = 8; mask >= 1; mask >>= 1) m = fmaxf(m, __shfl_xor(m, mask, 16));
  float e = act ? __expf(v - m) : 0.f;
  float sum = e;
  #pragma unroll
  for (int mask = 8; mask >= 1; mask >>= 1) sum += __shfl_xor(sum, mask, 16);
  if (act) out[(size_t)n * 10 + j] = (v - m) - __logf(sum);
}

// ======================= launch =======================
extern "C" void kernel_launch(void* const* d_in, const int* in_sizes, int n_in,
                              void* d_out, int out_size, void* d_ws, size_t ws_size,
                              hipStream_t stream) {
  const float* x    = (const float*)d_in[0];
  const int* eidx   = (const int*)d_in[1];
  const float* w1i  = (const float*)d_in[2];
  const float* w1r  = (const float*)d_in[3];
  const float* b1   = (const float*)d_in[4];
  const float* w2i  = (const float*)d_in[5];
  const float* w2r  = (const float*)d_in[6];
  const float* b2   = (const float*)d_in[7];
  const float* w3i  = (const float*)d_in[8];
  const float* w3r  = (const float*)d_in[9];
  const float* b3   = (const float*)d_in[10];
  float* out = (float*)d_out;

  const int N = in_sizes[0] / F_IN;     // 100000
  const int E = in_sizes[1] / 2;        // 3200000
  const int* row = eidx;
  const int* col = eidx + E;

  // workspace carve-up (256B aligned)
  char* p = (char*)d_ws;
  auto alloc = [&](size_t bytes) { void* r = (void*)p; p += (bytes + 255) & ~(size_t)255; return r; };
  int*   cnt  = (int*)alloc((size_t)N * 4);
  int*   off  = (int*)alloc((size_t)N * 4);
  int*   cur  = (int*)alloc((size_t)N * 4);
  float* dinv = (float*)alloc((size_t)N * 4);
  int*   bsum = (int*)alloc(1024);
  float* Wc   = (float*)alloc((size_t)F_IN * 32 * 4);
  float* W2c  = (float*)alloc((size_t)HD * 32 * 4);
  float* W3c  = (float*)alloc((size_t)HD * 20 * 4);
  int*   srow = (int*)alloc((size_t)E * 4);
  float* T    = (float*)alloc((size_t)N * 32 * 4);
  float* h    = (float*)alloc((size_t)N * HD * 4);

  const int nbE = (E + 255) / 256;
  const int nbScan = (N + 1023) / 1024;     // 98

  // edge sort (counting sort by col) + dinv
  hipMemsetAsync(cnt, 0, (size_t)N * 4, stream);
  k_hist <<<nbE, 256, 0, stream>>>(col, cnt, E);
  k_scan1<<<nbScan, 256, 0, stream>>>(cnt, off, bsum, N);
  k_scan2<<<1, 256, 0, stream>>>(bsum, nbScan);
  k_scan3<<<(N + 255) / 256, 256, 0, stream>>>(cnt, off, cur, dinv, bsum, N);
  k_build<<<nbE, 256, 0, stream>>>(row, col, cur, srow, E);

  // pack weights
  k_pack<<<(F_IN * 32 + 255) / 256, 256, 0, stream>>>(w1i, w1r, Wc, F_IN, 16);
  k_pack<<<(HD * 32 + 255) / 256, 256, 0, stream>>>(w2i, w2r, W2c, HD, 16);
  k_pack<<<(HD * 20 + 255) / 256, 256, 0, stream>>>(w3i, w3r, W3c, HD, 10);

  // layer 1
  k_gemm1<<<(N + G1_M - 1) / G1_M, 128, 0, stream>>>(x, Wc, dinv, T, N);
  k_gather_relu<<<(N + 15) / 16, 256, 0, stream>>>(T, off, cnt, srow, dinv, b1, h, N);
  // layer 2
  k_gemm_small<<<(N * 32 + 255) / 256, 256, 0, stream>>>(h, W2c, dinv, T, N, 32, 16);
  k_gather_relu<<<(N + 15) / 16, 256, 0, stream>>>(T, off, cnt, srow, dinv, b2, h, N);
  // layer 3 + internal relu + log_softmax
  k_gemm_small<<<(N * 32 + 255) / 256, 256, 0, stream>>>(h, W3c, dinv, T, N, 20, 10);
  k_gather_lsm<<<(N + 15) / 16, 256, 0, stream>>>(T, off, cnt, srow, dinv, b3, out, N);
}

// Round 4
// 1094.798 us; speedup vs baseline: 1.6309x; 1.1336x over previous
//
#include <hip/hip_runtime.h>
#include <hip/hip_bf16.h>
#include <cstdint>
#include <cstddef>

#define F_IN 767
#define HD   16

// ======================= counting-sort of edges by col =======================

__global__ void k_hist(const int* __restrict__ col, int* __restrict__ cnt, int E) {
  int e = blockIdx.x * 256 + threadIdx.x;
  if (e < E) atomicAdd(&cnt[col[e]], 1);
}

// block scan: 256 threads x 4 items = 1024 items/block.
__global__ void k_scan1(const int* __restrict__ cnt, int* __restrict__ off,
                        int* __restrict__ bsum, int N) {
  __shared__ int lds[256];
  int t = threadIdx.x;
  int base = blockIdx.x * 1024 + t * 4;
  int4 v = make_int4(0, 0, 0, 0);
  if (base + 3 < N) {
    v = *(const int4*)&cnt[base];
  } else {
    if (base + 0 < N) v.x = cnt[base + 0];
    if (base + 1 < N) v.y = cnt[base + 1];
    if (base + 2 < N) v.z = cnt[base + 2];
    if (base + 3 < N) v.w = cnt[base + 3];
  }
  int s = v.x + v.y + v.z + v.w;
  lds[t] = s;
  __syncthreads();
  for (int d = 1; d < 256; d <<= 1) {
    int add = (t >= d) ? lds[t - d] : 0;
    __syncthreads();
    lds[t] += add;
    __syncthreads();
  }
  int excl = lds[t] - s;
  if (t == 255) bsum[blockIdx.x] = lds[255];
  int run = excl;
  if (base + 0 < N) off[base + 0] = run; run += v.x;
  if (base + 1 < N) off[base + 1] = run; run += v.y;
  if (base + 2 < N) off[base + 2] = run; run += v.z;
  if (base + 3 < N) off[base + 3] = run;
}

// single block: exclusive scan of block sums in place (nb <= 256)
__global__ void k_scan2(int* __restrict__ bsum, int nb) {
  __shared__ int lds[256];
  int t = threadIdx.x;
  int s = (t < nb) ? bsum[t] : 0;
  lds[t] = s;
  __syncthreads();
  for (int d = 1; d < 256; d <<= 1) {
    int add = (t >= d) ? lds[t - d] : 0;
    __syncthreads();
    lds[t] += add;
    __syncthreads();
  }
  if (t < nb) bsum[t] = lds[t] - s;
}

// finalize offsets, copy to cursor, compute dinv
__global__ void k_scan3(const int* __restrict__ cnt, int* __restrict__ off,
                        int* __restrict__ cur, float* __restrict__ dinv,
                        const int* __restrict__ bsum, int N) {
  int i = blockIdx.x * 256 + threadIdx.x;
  if (i < N) {
    int o = off[i] + bsum[i >> 10];
    off[i] = o;
    cur[i] = o;
    int c = cnt[i];
    dinv[i] = (c > 0) ? rsqrtf((float)c) : 0.f;
  }
}

// ======================= two-phase edge partition (replaces one-pass k_build) ==================
// Phase A buckets edges by col>>9 into tmp with coalesced run writes (fixes the
// 194MB write-allocate amplification of the random 4B scatter). Phase B places
// within-bucket: all writes confined to a ~64KB srow region -> L2-resident.
#define PSH     9
#define PA_TILE 4096

__global__ void k_binit(const int* __restrict__ off, int* __restrict__ bcur, int N, int E) {
  int b = threadIdx.x;              // 256 entries
  int cb = b << PSH;
  bcur[b] = (cb < N) ? off[cb] : E;
}

__global__ __launch_bounds__(256) void k_part(const int* __restrict__ row,
                                              const int* __restrict__ col,
                                              int* __restrict__ bcur,
                                              int2* __restrict__ tmp, int E) {
  __shared__ int  hcnt[256];
  __shared__ int  hoff[256];
  __shared__ int  hcur[256];
  __shared__ int  gbase[256];
  __shared__ int2 st[PA_TILE];      // 32 KB
  int t = threadIdx.x;
  int tile = blockIdx.x * PA_TILE;
  int nE = min(PA_TILE, E - tile);

  hcnt[t] = 0;
  __syncthreads();

  int r[16], c[16];
  #pragma unroll
  for (int i = 0; i < 16; ++i) {
    int li = i * 256 + t;
    if (li < nE) {
      r[i] = row[tile + li];
      c[i] = col[tile + li];
      atomicAdd(&hcnt[c[i] >> PSH], 1);
    } else c[i] = -1;
  }
  __syncthreads();

  // inclusive scan of hcnt -> hoff
  int s = hcnt[t];
  hoff[t] = s;
  __syncthreads();
  for (int d = 1; d < 256; d <<= 1) {
    int add = (t >= d) ? hoff[t - d] : 0;
    __syncthreads();
    hoff[t] += add;
    __syncthreads();
  }
  int excl = hoff[t] - s;
  hcur[t] = excl;
  gbase[t] = (s > 0) ? atomicAdd(&bcur[t], s) : 0;
  __syncthreads();

  // rebin into LDS staging
  #pragma unroll
  for (int i = 0; i < 16; ++i) {
    if (c[i] >= 0) {
      int p = atomicAdd(&hcur[c[i] >> PSH], 1);
      st[p] = make_int2(r[i], c[i]);
    }
  }
  __syncthreads();

  // flush: contiguous runs per bucket -> coalesced global writes
  #pragma unroll
  for (int i = 0; i < 16; ++i) {
    int idx = i * 256 + t;
    if (idx < nE) {
      int2 v = st[idx];
      int b = v.y >> PSH;
      tmp[gbase[b] + (idx - (hoff[b] - hcnt[b]))] = v;
    }
  }
}

#define PLS 4   // splits per bucket
__global__ __launch_bounds__(256) void k_place(const int2* __restrict__ tmp,
                                               const int* __restrict__ off,
                                               int* __restrict__ cur,
                                               int* __restrict__ srow, int N, int E) {
  int b = blockIdx.x / PLS, sp = blockIdx.x % PLS;
  int cb = b << PSH;
  if (cb >= N) return;
  int start = off[cb];
  int nx = (b + 1) << PSH;
  int end = (nx < N) ? off[nx] : E;
  int len = end - start;
  int per = (len + PLS - 1) / PLS;
  int s0 = start + sp * per;
  int s1 = min(s0 + per, end);
  for (int e = s0 + threadIdx.x; e < s1; e += 256) {
    int2 v = tmp[e];
    int p = atomicAdd(&cur[v.y], 1);
    srow[p] = v.x;
  }
}

// ======================= weight pack: f32 [wi | wr] -> f32 Wc[K][2H] =======================
__global__ void k_pack(const float* __restrict__ wi, const float* __restrict__ wr,
                       float* __restrict__ Wc, int K, int H) {
  int i = blockIdx.x * 256 + threadIdx.x;
  int tot = K * 2 * H;
  if (i < tot) {
    int k = i / (2 * H), c = i % (2 * H);
    Wc[i] = (c < H) ? wi[k * H + c] : wr[k * H + (c - H)];
  }
}

// ======================= GEMM1: x[N,767](f32) @ Wc[767,32](f32) -> T[N,32](f32) =======================
// M=64 rows/block, 128 threads, 4x4 thread tile, reg-staged double-buffered pipeline.
// xs XOR-swizzled at float4-quad granularity. dinv[row] folded into cols 0..15.
#define G1_KC  32     // k per chunk
#define G1_M   64     // rows per block

__global__ __launch_bounds__(128) void k_gemm1(const float* __restrict__ x,
                                               const float* __restrict__ Wc,
                                               const float* __restrict__ dinv,
                                               float* __restrict__ T, int N) {
  __shared__ __align__(16) float xs[2][G1_KC * G1_M];
  __shared__ __align__(16) float ws[2][G1_KC * 32];
  int t = threadIdx.x;
  int tn = t & 7;
  int tm = t >> 3;
  int rowBase = blockIdx.x * G1_M;

  int kl = t & 15;
  int rr = t >> 4;
  int sxw = kl & 7;

  float xv[16];
  float wv[8];

  const int NC = (F_IN + G1_KC - 1) / G1_KC;   // 24

  float acc[4][4];
  #pragma unroll
  for (int m = 0; m < 4; ++m)
    #pragma unroll
    for (int c = 0; c < 4; ++c) acc[m][c] = 0.f;

  {
    const int kc = 0;
    #pragma unroll
    for (int kh = 0; kh < 2; ++kh) {
      int kg = kc + kh * 16 + kl;
      #pragma unroll
      for (int i = 0; i < 8; ++i) {
        int gr = rowBase + i * 8 + rr;
        float v = 0.f;
        if (gr < N) v = x[(size_t)gr * F_IN + kg];
        xv[i * 2 + kh] = v;
      }
    }
    #pragma unroll
    for (int i = 0; i < 8; ++i) {
      int idx = i * 128 + t;
      int wk = idx >> 5, wc = idx & 31;
      wv[i] = Wc[(size_t)(kc + wk) * 32 + wc];
    }
    #pragma unroll
    for (int kh = 0; kh < 2; ++kh)
      #pragma unroll
      for (int i = 0; i < 8; ++i) {
        int r = i * 8 + rr;
        int q = r >> 2, j = r & 3;
        xs[0][(kh * 16 + kl) * G1_M + ((q ^ sxw) << 2) + j] = xv[i * 2 + kh];
      }
    #pragma unroll
    for (int i = 0; i < 8; ++i) ws[0][i * 128 + t] = wv[i];
  }
  __syncthreads();

  for (int c = 0; c < NC; ++c) {
    int b = c & 1;
    if (c + 1 < NC) {
      int kc = (c + 1) * G1_KC;
      #pragma unroll
      for (int kh = 0; kh < 2; ++kh) {
        int kg = kc + kh * 16 + kl;
        bool kval = (kg < F_IN);
        #pragma unroll
        for (int i = 0; i < 8; ++i) {
          int gr = rowBase + i * 8 + rr;
          float v = 0.f;
          if (kval && gr < N) v = x[(size_t)gr * F_IN + kg];
          xv[i * 2 + kh] = v;
        }
      }
      #pragma unroll
      for (int i = 0; i < 8; ++i) {
        int idx = i * 128 + t;
        int wk = idx >> 5, wc = idx & 31;
        int kg = kc + wk;
        wv[i] = (kg < F_IN) ? Wc[(size_t)kg * 32 + wc] : 0.f;
      }
    }
    const float* xb = &xs[b][0];
    const float* wb = &ws[b][0];
    #pragma unroll
    for (int kk = 0; kk < G1_KC; ++kk) {
      const int s = kk & 7;
      float4 a  = *(const float4*)&xb[kk * G1_M + ((tm ^ s) << 2)];
      float4 bv = *(const float4*)&wb[kk * 32 + tn * 4];
      float am[4] = {a.x, a.y, a.z, a.w};
      float bn[4] = {bv.x, bv.y, bv.z, bv.w};
      #pragma unroll
      for (int m = 0; m < 4; ++m)
        #pragma unroll
        for (int cc = 0; cc < 4; ++cc) acc[m][cc] += am[m] * bn[cc];
    }
    if (c + 1 < NC) {
      __syncthreads();
      #pragma unroll
      for (int kh = 0; kh < 2; ++kh)
        #pragma unroll
        for (int i = 0; i < 8; ++i) {
          int r = i * 8 + rr;
          int q = r >> 2, j = r & 3;
          xs[b ^ 1][(kh * 16 + kl) * G1_M + ((q ^ sxw) << 2) + j] = xv[i * 2 + kh];
        }
      #pragma unroll
      for (int i = 0; i < 8; ++i) ws[b ^ 1][i * 128 + t] = wv[i];
      __syncthreads();
    }
  }

  #pragma unroll
  for (int m = 0; m < 4; ++m) {
    int r = rowBase + tm * 4 + m;
    if (r < N) {
      float4 o = make_float4(acc[m][0], acc[m][1], acc[m][2], acc[m][3]);
      if (tn < 4) {
        float d = dinv[r];
        o.x *= d; o.y *= d; o.z *= d; o.w *= d;
      }
      *(float4*)&T[(size_t)r * 32 + tn * 4] = o;
    }
  }
}

// ======================= small GEMM: h[N,16](f32) @ W[16,P](f32) -> T[N,P](f32) =======================
__global__ void k_gemm_small(const float* __restrict__ h, const float* __restrict__ W,
                             const float* __restrict__ dinv,
                             float* __restrict__ T, int N, int P, int SC) {
  int idx = blockIdx.x * 256 + threadIdx.x;
  int n = idx >> 5, c = idx & 31;
  if (n < N && c < P) {
    float acc = 0.f;
    #pragma unroll
    for (int k = 0; k < HD; ++k) acc += h[(size_t)n * HD + k] * W[k * P + c];
    if (c < SC) acc *= dinv[n];
    T[(size_t)n * P + c] = acc;
  }
}

// ======================= gather + relu epilogue (layers 1,2) =======================
__global__ void k_gather_relu(const float* __restrict__ T, const int* __restrict__ off,
                              const int* __restrict__ cnt, const int* __restrict__ srow,
                              const float* __restrict__ dinv, const float* __restrict__ bias,
                              float* __restrict__ hout, int N) {
  int t = threadIdx.x;
  int j = t & 15, ln = t >> 4;
  int n = blockIdx.x * 16 + ln;
  if (n >= N) return;
  int s = off[n], c = cnt[n];
  float acc = 0.f;
  for (int p = s; p < s + c; ++p) {
    int r = srow[p];
    acc += T[(size_t)r * 32 + j];
  }
  float v = dinv[n] * acc + T[(size_t)n * 32 + 16 + j] + bias[j];
  hout[(size_t)n * HD + j] = fmaxf(v, 0.f);
}

// ======================= gather + relu + log_softmax (layer 3, C=10, pitch 20), f32 out ===========
__global__ void k_gather_lsm(const float* __restrict__ T, const int* __restrict__ off,
                             const int* __restrict__ cnt, const int* __restrict__ srow,
                             const float* __restrict__ dinv, const float* __restrict__ b3,
                             float* __restrict__ out, int N) {
  int t = threadIdx.x;
  int j = t & 15, ln = t >> 4;
  int n = blockIdx.x * 16 + ln;
  bool act = (n < N) && (j < 10);
  float v = -1e30f;
  if (act) {
    int s = off[n], c = cnt[n];
    float acc = 0.f;
    for (int p = s; p < s + c; ++p) {
      int r = srow[p];
      acc += T[(size_t)r * 20 + j];
    }
    v = dinv[n] * acc + T[(size_t)n * 20 + 10 + j] + b3[j];
    v = fmaxf(v, 0.f);   // ARMAConv internal relu on conv3 output
  }
  float m = v;
  #pragma unroll
  for (int mask = 8; mask >= 1; mask >>= 1) m = fmaxf(m, __shfl_xor(m, mask, 16));
  float e = act ? __expf(v - m) : 0.f;
  float sum = e;
  #pragma unroll
  for (int mask = 8; mask >= 1; mask >>= 1) sum += __shfl_xor(sum, mask, 16);
  if (act) out[(size_t)n * 10 + j] = (v - m) - __logf(sum);
}

// ======================= launch =======================
extern "C" void kernel_launch(void* const* d_in, const int* in_sizes, int n_in,
                              void* d_out, int out_size, void* d_ws, size_t ws_size,
                              hipStream_t stream) {
  const float* x    = (const float*)d_in[0];
  const int* eidx   = (const int*)d_in[1];
  const float* w1i  = (const float*)d_in[2];
  const float* w1r  = (const float*)d_in[3];
  const float* b1   = (const float*)d_in[4];
  const float* w2i  = (const float*)d_in[5];
  const float* w2r  = (const float*)d_in[6];
  const float* b2   = (const float*)d_in[7];
  const float* w3i  = (const float*)d_in[8];
  const float* w3r  = (const float*)d_in[9];
  const float* b3   = (const float*)d_in[10];
  float* out = (float*)d_out;

  const int N = in_sizes[0] / F_IN;     // 100000
  const int E = in_sizes[1] / 2;        // 3200000
  const int* row = eidx;
  const int* col = eidx + E;

  // workspace carve-up (256B aligned)
  char* p = (char*)d_ws;
  auto alloc = [&](size_t bytes) { void* r = (void*)p; p += (bytes + 255) & ~(size_t)255; return r; };
  int*   cnt  = (int*)alloc((size_t)N * 4);
  int*   off  = (int*)alloc((size_t)N * 4);
  int*   cur  = (int*)alloc((size_t)N * 4);
  float* dinv = (float*)alloc((size_t)N * 4);
  int*   bsum = (int*)alloc(1024);
  int*   bcur = (int*)alloc(1024);
  float* Wc   = (float*)alloc((size_t)F_IN * 32 * 4);
  float* W2c  = (float*)alloc((size_t)HD * 32 * 4);
  float* W3c  = (float*)alloc((size_t)HD * 20 * 4);
  int*   srow = (int*)alloc((size_t)E * 4);
  // tmp (E*8) is aliased by T (N*32*4) + h (N*16*4): tmp is consumed by k_place
  // before gemm1 first writes T.  E*8 = 25.6MB >= 19.2MB.
  char*  big  = (char*)alloc((size_t)E * 8);
  int2*  tmp  = (int2*)big;
  float* T    = (float*)big;
  float* h    = (float*)(big + (size_t)N * 32 * 4);

  const int nbE = (E + 255) / 256;
  const int nbScan = (N + 1023) / 1024;     // 98
  const int nBuck = (N + (1 << PSH) - 1) >> PSH;   // 196

  // edge sort (counting sort by col, two-phase bucket partition) + dinv
  hipMemsetAsync(cnt, 0, (size_t)N * 4, stream);
  k_hist <<<nbE, 256, 0, stream>>>(col, cnt, E);
  k_scan1<<<nbScan, 256, 0, stream>>>(cnt, off, bsum, N);
  k_scan2<<<1, 256, 0, stream>>>(bsum, nbScan);
  k_scan3<<<(N + 255) / 256, 256, 0, stream>>>(cnt, off, cur, dinv, bsum, N);
  k_binit<<<1, 256, 0, stream>>>(off, bcur, N, E);
  k_part <<<(E + PA_TILE - 1) / PA_TILE, 256, 0, stream>>>(row, col, bcur, tmp, E);
  k_place<<<nBuck * PLS, 256, 0, stream>>>(tmp, off, cur, srow, N, E);

  // pack weights
  k_pack<<<(F_IN * 32 + 255) / 256, 256, 0, stream>>>(w1i, w1r, Wc, F_IN, 16);
  k_pack<<<(HD * 32 + 255) / 256, 256, 0, stream>>>(w2i, w2r, W2c, HD, 16);
  k_pack<<<(HD * 20 + 255) / 256, 256, 0, stream>>>(w3i, w3r, W3c, HD, 10);

  // layer 1
  k_gemm1<<<(N + G1_M - 1) / G1_M, 128, 0, stream>>>(x, Wc, dinv, T, N);
  k_gather_relu<<<(N + 15) / 16, 256, 0, stream>>>(T, off, cnt, srow, dinv, b1, h, N);
  // layer 2
  k_gemm_small<<<(N * 32 + 255) / 256, 256, 0, stream>>>(h, W2c, dinv, T, N, 32, 16);
  k_gather_relu<<<(N + 15) / 16, 256, 0, stream>>>(T, off, cnt, srow, dinv, b2, h, N);
  // layer 3 + internal relu + log_softmax
  k_gemm_small<<<(N * 32 + 255) / 256, 256, 0, stream>>>(h, W3c, dinv, T, N, 20, 10);
  k_gather_lsm<<<(N + 15) / 16, 256, 0, stream>>>(T, off, cnt, srow, dinv, b3, out, N);
}

// Round 5
// 934.421 us; speedup vs baseline: 1.9108x; 1.1716x over previous
//
#include <hip/hip_runtime.h>
#include <hip/hip_bf16.h>
#include <cstdint>
#include <cstddef>

#define F_IN 767
#define HD   16

typedef __attribute__((ext_vector_type(8))) short short8v;   // 8 bf16 (4 VGPR) MFMA A/B frag
typedef __attribute__((ext_vector_type(4))) float float4v;   // MFMA C/D frag
typedef float __attribute__((ext_vector_type(4), aligned(4))) float4a;  // 4B-aligned vector load

static __device__ __forceinline__ unsigned short f2bf(float f) {
  unsigned int u = __float_as_uint(f);
  return (unsigned short)((u + 0x7fffu + ((u >> 16) & 1u)) >> 16);   // RNE
}
static __device__ __forceinline__ float bf2f(unsigned short b) {
  return __uint_as_float(((unsigned int)b) << 16);
}

// ======================= counting-sort of edges by col =======================

__global__ void k_hist(const int* __restrict__ col, int* __restrict__ cnt, int E) {
  int e = blockIdx.x * 256 + threadIdx.x;
  if (e < E) atomicAdd(&cnt[col[e]], 1);
}

// block scan: 256 threads x 4 items = 1024 items/block.
__global__ void k_scan1(const int* __restrict__ cnt, int* __restrict__ off,
                        int* __restrict__ bsum, int N) {
  __shared__ int lds[256];
  int t = threadIdx.x;
  int base = blockIdx.x * 1024 + t * 4;
  int4 v = make_int4(0, 0, 0, 0);
  if (base + 3 < N) {
    v = *(const int4*)&cnt[base];
  } else {
    if (base + 0 < N) v.x = cnt[base + 0];
    if (base + 1 < N) v.y = cnt[base + 1];
    if (base + 2 < N) v.z = cnt[base + 2];
    if (base + 3 < N) v.w = cnt[base + 3];
  }
  int s = v.x + v.y + v.z + v.w;
  lds[t] = s;
  __syncthreads();
  for (int d = 1; d < 256; d <<= 1) {
    int add = (t >= d) ? lds[t - d] : 0;
    __syncthreads();
    lds[t] += add;
    __syncthreads();
  }
  int excl = lds[t] - s;
  if (t == 255) bsum[blockIdx.x] = lds[255];
  int run = excl;
  if (base + 0 < N) off[base + 0] = run; run += v.x;
  if (base + 1 < N) off[base + 1] = run; run += v.y;
  if (base + 2 < N) off[base + 2] = run; run += v.z;
  if (base + 3 < N) off[base + 3] = run;
}

// single block: exclusive scan of block sums in place (nb <= 256)
__global__ void k_scan2(int* __restrict__ bsum, int nb) {
  __shared__ int lds[256];
  int t = threadIdx.x;
  int s = (t < nb) ? bsum[t] : 0;
  lds[t] = s;
  __syncthreads();
  for (int d = 1; d < 256; d <<= 1) {
    int add = (t >= d) ? lds[t - d] : 0;
    __syncthreads();
    lds[t] += add;
    __syncthreads();
  }
  if (t < nb) bsum[t] = lds[t] - s;
}

// finalize offsets, copy to cursor, compute dinv
__global__ void k_scan3(const int* __restrict__ cnt, int* __restrict__ off,
                        int* __restrict__ cur, float* __restrict__ dinv,
                        const int* __restrict__ bsum, int N) {
  int i = blockIdx.x * 256 + threadIdx.x;
  if (i < N) {
    int o = off[i] + bsum[i >> 10];
    off[i] = o;
    cur[i] = o;
    int c = cnt[i];
    dinv[i] = (c > 0) ? rsqrtf((float)c) : 0.f;
  }
}

// ======================= two-phase edge partition =======================
#define PSH     9
#define PA_TILE 4096

__global__ void k_binit(const int* __restrict__ off, int* __restrict__ bcur, int N, int E) {
  int b = threadIdx.x;
  int cb = b << PSH;
  bcur[b] = (cb < N) ? off[cb] : E;
}

__global__ __launch_bounds__(256) void k_part(const int* __restrict__ row,
                                              const int* __restrict__ col,
                                              int* __restrict__ bcur,
                                              int2* __restrict__ tmp, int E) {
  __shared__ int  hcnt[256];
  __shared__ int  hoff[256];
  __shared__ int  hcur[256];
  __shared__ int  gbase[256];
  __shared__ int2 st[PA_TILE];      // 32 KB
  int t = threadIdx.x;
  int tile = blockIdx.x * PA_TILE;
  int nE = min(PA_TILE, E - tile);

  hcnt[t] = 0;
  __syncthreads();

  int r[16], c[16];
  #pragma unroll
  for (int i = 0; i < 16; ++i) {
    int li = i * 256 + t;
    if (li < nE) {
      r[i] = row[tile + li];
      c[i] = col[tile + li];
      atomicAdd(&hcnt[c[i] >> PSH], 1);
    } else c[i] = -1;
  }
  __syncthreads();

  int s = hcnt[t];
  hoff[t] = s;
  __syncthreads();
  for (int d = 1; d < 256; d <<= 1) {
    int add = (t >= d) ? hoff[t - d] : 0;
    __syncthreads();
    hoff[t] += add;
    __syncthreads();
  }
  int excl = hoff[t] - s;
  hcur[t] = excl;
  gbase[t] = (s > 0) ? atomicAdd(&bcur[t], s) : 0;
  __syncthreads();

  #pragma unroll
  for (int i = 0; i < 16; ++i) {
    if (c[i] >= 0) {
      int p = atomicAdd(&hcur[c[i] >> PSH], 1);
      st[p] = make_int2(r[i], c[i]);
    }
  }
  __syncthreads();

  #pragma unroll
  for (int i = 0; i < 16; ++i) {
    int idx = i * 256 + t;
    if (idx < nE) {
      int2 v = st[idx];
      int b = v.y >> PSH;
      tmp[gbase[b] + (idx - (hoff[b] - hcnt[b]))] = v;
    }
  }
}

#define PLS 4
__global__ __launch_bounds__(256) void k_place(const int2* __restrict__ tmp,
                                               const int* __restrict__ off,
                                               int* __restrict__ cur,
                                               int* __restrict__ srow, int N, int E) {
  int b = blockIdx.x / PLS, sp = blockIdx.x % PLS;
  int cb = b << PSH;
  if (cb >= N) return;
  int start = off[cb];
  int nx = (b + 1) << PSH;
  int end = (nx < N) ? off[nx] : E;
  int len = end - start;
  int per = (len + PLS - 1) / PLS;
  int s0 = start + sp * per;
  int s1 = min(s0 + per, end);
  for (int e = s0 + threadIdx.x; e < s1; e += 256) {
    int2 v = tmp[e];
    int p = atomicAdd(&cur[v.y], 1);
    srow[p] = v.x;
  }
}

// ======================= weight pack: f32 [wi | wr] -> f32 Wc[K][2H] =======================
__global__ void k_pack(const float* __restrict__ wi, const float* __restrict__ wr,
                       float* __restrict__ Wc, int K, int H) {
  int i = blockIdx.x * 256 + threadIdx.x;
  int tot = K * 2 * H;
  if (i < tot) {
    int k = i / (2 * H), c = i % (2 * H);
    Wc[i] = (c < H) ? wi[k * H + c] : wr[k * H + (c - H)];
  }
}

// ======================= B-fragment pre-pack for MFMA GEMM1 =======================
// Bf layout: [s(24)][term(2: hi,lo)][half(2)][lane(64)][elem(8)] bf16 bits.
// B[k][col]: col = half*16 + (lane&15); k = s*32 + (lane>>4)*8 + elem.
// Same (lane-group, elem)->k map is used for A, so any internal HW k-permutation
// cancels (operand-consistent slot assignment).
__global__ void k_packbf(const float* __restrict__ wi, const float* __restrict__ wr,
                         unsigned short* __restrict__ Bf) {
  int idx = blockIdx.x * 256 + threadIdx.x;
  if (idx >= 24 * 2 * 2 * 64 * 8) return;
  int j    = idx & 7;
  int l    = (idx >> 3) & 63;
  int half = (idx >> 9) & 1;
  int term = (idx >> 10) & 1;
  int s    = idx >> 11;
  int col  = half * 16 + (l & 15);
  int k    = s * 32 + (l >> 4) * 8 + j;
  float w = 0.f;
  if (k < F_IN) w = (col < 16) ? wi[k * 16 + col] : wr[k * 16 + (col - 16)];
  unsigned short hi = f2bf(w);
  unsigned short lo = f2bf(w - bf2f(hi));
  Bf[idx] = (term == 0) ? hi : lo;
}

// ======================= GEMM1 via bf16 MFMA, 3-term f32-split =======================
// x[N,767] f32 @ W[767,32] -> T[N,32] f32.  x = xh + xl (bf16 pair), W likewise;
// C += xh*wh + xh*wl + xl*wh  (err ~2^-16 rel).  No LDS, no barriers:
// 4 waves/block, each wave owns 16 rows x 32 cols; A loaded straight from x
// (32B per lane of its own row), converted in-registers; B frags from the
// pre-packed 96KB table (L2-resident).  dinv[row] folded into cols 0..15.
__global__ __launch_bounds__(256) void k_gemm1(const float* __restrict__ x,
                                               const unsigned short* __restrict__ Bf,
                                               const float* __restrict__ dinv,
                                               float* __restrict__ T, int N) {
  int t = threadIdx.x;
  int w = t >> 6, l = t & 63;
  int kg = l >> 4;                       // 0..3
  int rowA = blockIdx.x * 64 + w * 16 + (l & 15);
  const float* xr = x + (size_t)min(rowA, N - 1) * F_IN;
  const short8v* Bfv = (const short8v*)Bf;

  float4v c0 = {0.f, 0.f, 0.f, 0.f};
  float4v c1 = {0.f, 0.f, 0.f, 0.f};

  for (int s = 0; s < 24; ++s) {
    int kbase = s * 32 + kg * 8;
    float v[8];
    if (s < 23) {
      float4a a = *(const float4a*)(xr + kbase);
      float4a b = *(const float4a*)(xr + kbase + 4);
      v[0] = a.x; v[1] = a.y; v[2] = a.z; v[3] = a.w;
      v[4] = b.x; v[5] = b.y; v[6] = b.z; v[7] = b.w;
    } else {
      #pragma unroll
      for (int j = 0; j < 8; ++j) {
        int k = kbase + j;
        v[j] = (k < F_IN) ? xr[k] : 0.f;
      }
    }
    short8v ah, al;
    #pragma unroll
    for (int j = 0; j < 8; ++j) {
      unsigned short h = f2bf(v[j]);
      ah[j] = (short)h;
      al[j] = (short)f2bf(v[j] - bf2f(h));
    }
    short8v bh0 = Bfv[(s * 4 + 0) * 64 + l];
    short8v bh1 = Bfv[(s * 4 + 1) * 64 + l];
    short8v bl0 = Bfv[(s * 4 + 2) * 64 + l];
    short8v bl1 = Bfv[(s * 4 + 3) * 64 + l];
    c0 = __builtin_amdgcn_mfma_f32_16x16x32_bf16(ah, bh0, c0, 0, 0, 0);
    c1 = __builtin_amdgcn_mfma_f32_16x16x32_bf16(ah, bh1, c1, 0, 0, 0);
    c0 = __builtin_amdgcn_mfma_f32_16x16x32_bf16(al, bh0, c0, 0, 0, 0);
    c1 = __builtin_amdgcn_mfma_f32_16x16x32_bf16(al, bh1, c1, 0, 0, 0);
    c0 = __builtin_amdgcn_mfma_f32_16x16x32_bf16(ah, bl0, c0, 0, 0, 0);
    c1 = __builtin_amdgcn_mfma_f32_16x16x32_bf16(ah, bl1, c1, 0, 0, 0);
  }

  // C/D layout (HW-verified): col = lane&15, row = (lane>>4)*4 + reg
  int rowC = blockIdx.x * 64 + w * 16 + (l >> 4) * 4;
  int colC = l & 15;
  #pragma unroll
  for (int j = 0; j < 4; ++j) {
    int gr = rowC + j;
    if (gr < N) {
      float d = dinv[gr];
      T[(size_t)gr * 32 + colC]      = c0[j] * d;
      T[(size_t)gr * 32 + 16 + colC] = c1[j];
    }
  }
}

// ======================= small GEMM: h[N,16](f32) @ W[16,P](f32) -> T[N,P](f32) =======================
__global__ void k_gemm_small(const float* __restrict__ h, const float* __restrict__ W,
                             const float* __restrict__ dinv,
                             float* __restrict__ T, int N, int P, int SC) {
  int idx = blockIdx.x * 256 + threadIdx.x;
  int n = idx >> 5, c = idx & 31;
  if (n < N && c < P) {
    float acc = 0.f;
    #pragma unroll
    for (int k = 0; k < HD; ++k) acc += h[(size_t)n * HD + k] * W[k * P + c];
    if (c < SC) acc *= dinv[n];
    T[(size_t)n * P + c] = acc;
  }
}

// ======================= gather + relu epilogue (layers 1,2) =======================
// 4-wide unrolled edge loop for memory-level parallelism (same FP add order).
__global__ void k_gather_relu(const float* __restrict__ T, const int* __restrict__ off,
                              const int* __restrict__ cnt, const int* __restrict__ srow,
                              const float* __restrict__ dinv, const float* __restrict__ bias,
                              float* __restrict__ hout, int N) {
  int t = threadIdx.x;
  int j = t & 15, ln = t >> 4;
  int n = blockIdx.x * 16 + ln;
  if (n >= N) return;
  int s = off[n], c = cnt[n];
  float acc = 0.f;
  int p = s, e4 = s + (c & ~3);
  for (; p < e4; p += 4) {
    int r0 = srow[p], r1 = srow[p + 1], r2 = srow[p + 2], r3 = srow[p + 3];
    float v0 = T[(size_t)r0 * 32 + j];
    float v1 = T[(size_t)r1 * 32 + j];
    float v2 = T[(size_t)r2 * 32 + j];
    float v3 = T[(size_t)r3 * 32 + j];
    acc += v0; acc += v1; acc += v2; acc += v3;
  }
  for (; p < s + c; ++p) acc += T[(size_t)srow[p] * 32 + j];
  float v = dinv[n] * acc + T[(size_t)n * 32 + 16 + j] + bias[j];
  hout[(size_t)n * HD + j] = fmaxf(v, 0.f);
}

// ======================= gather + relu + log_softmax (layer 3, C=10, pitch 20) ===========
__global__ void k_gather_lsm(const float* __restrict__ T, const int* __restrict__ off,
                             const int* __restrict__ cnt, const int* __restrict__ srow,
                             const float* __restrict__ dinv, const float* __restrict__ b3,
                             float* __restrict__ out, int N) {
  int t = threadIdx.x;
  int j = t & 15, ln = t >> 4;
  int n = blockIdx.x * 16 + ln;
  bool act = (n < N) && (j < 10);
  float v = -1e30f;
  if (act) {
    int s = off[n], c = cnt[n];
    float acc = 0.f;
    int p = s, e4 = s + (c & ~3);
    for (; p < e4; p += 4) {
      int r0 = srow[p], r1 = srow[p + 1], r2 = srow[p + 2], r3 = srow[p + 3];
      float v0 = T[(size_t)r0 * 20 + j];
      float v1 = T[(size_t)r1 * 20 + j];
      float v2 = T[(size_t)r2 * 20 + j];
      float v3 = T[(size_t)r3 * 20 + j];
      acc += v0; acc += v1; acc += v2; acc += v3;
    }
    for (; p < s + c; ++p) acc += T[(size_t)srow[p] * 20 + j];
    v = dinv[n] * acc + T[(size_t)n * 20 + 10 + j] + b3[j];
    v = fmaxf(v, 0.f);   // ARMAConv internal relu on conv3 output
  }
  float m = v;
  #pragma unroll
  for (int mask = 8; mask >= 1; mask >>= 1) m = fmaxf(m, __shfl_xor(m, mask, 16));
  float e = act ? __expf(v - m) : 0.f;
  float sum = e;
  #pragma unroll
  for (int mask = 8; mask >= 1; mask >>= 1) sum += __shfl_xor(sum, mask, 16);
  if (act) out[(size_t)n * 10 + j] = (v - m) - __logf(sum);
}

// ======================= launch =======================
extern "C" void kernel_launch(void* const* d_in, const int* in_sizes, int n_in,
                              void* d_out, int out_size, void* d_ws, size_t ws_size,
                              hipStream_t stream) {
  const float* x    = (const float*)d_in[0];
  const int* eidx   = (const int*)d_in[1];
  const float* w1i  = (const float*)d_in[2];
  const float* w1r  = (const float*)d_in[3];
  const float* b1   = (const float*)d_in[4];
  const float* w2i  = (const float*)d_in[5];
  const float* w2r  = (const float*)d_in[6];
  const float* b2   = (const float*)d_in[7];
  const float* w3i  = (const float*)d_in[8];
  const float* w3r  = (const float*)d_in[9];
  const float* b3   = (const float*)d_in[10];
  float* out = (float*)d_out;

  const int N = in_sizes[0] / F_IN;     // 100000
  const int E = in_sizes[1] / 2;        // 3200000
  const int* row = eidx;
  const int* col = eidx + E;

  // workspace carve-up (256B aligned)
  char* p = (char*)d_ws;
  auto alloc = [&](size_t bytes) { void* r = (void*)p; p += (bytes + 255) & ~(size_t)255; return r; };
  int*   cnt  = (int*)alloc((size_t)N * 4);
  int*   off  = (int*)alloc((size_t)N * 4);
  int*   cur  = (int*)alloc((size_t)N * 4);
  float* dinv = (float*)alloc((size_t)N * 4);
  int*   bsum = (int*)alloc(1024);
  int*   bcur = (int*)alloc(1024);
  unsigned short* Bf = (unsigned short*)alloc((size_t)24 * 2 * 2 * 64 * 8 * 2);   // 96 KB
  float* W2c  = (float*)alloc((size_t)HD * 32 * 4);
  float* W3c  = (float*)alloc((size_t)HD * 20 * 4);
  int*   srow = (int*)alloc((size_t)E * 4);
  // tmp (E*8) aliased by T (N*32*4) + h (N*16*4): tmp fully consumed by k_place
  // before gemm1 first writes T.  E*8 = 25.6MB >= 19.2MB.
  char*  big  = (char*)alloc((size_t)E * 8);
  int2*  tmp  = (int2*)big;
  float* T    = (float*)big;
  float* h    = (float*)(big + (size_t)N * 32 * 4);

  const int nbE = (E + 255) / 256;
  const int nbScan = (N + 1023) / 1024;     // 98
  const int nBuck = (N + (1 << PSH) - 1) >> PSH;   // 196

  // edge sort (counting sort by col, two-phase bucket partition) + dinv
  hipMemsetAsync(cnt, 0, (size_t)N * 4, stream);
  k_hist <<<nbE, 256, 0, stream>>>(col, cnt, E);
  k_scan1<<<nbScan, 256, 0, stream>>>(cnt, off, bsum, N);
  k_scan2<<<1, 256, 0, stream>>>(bsum, nbScan);
  k_scan3<<<(N + 255) / 256, 256, 0, stream>>>(cnt, off, cur, dinv, bsum, N);
  k_binit<<<1, 256, 0, stream>>>(off, bcur, N, E);
  k_part <<<(E + PA_TILE - 1) / PA_TILE, 256, 0, stream>>>(row, col, bcur, tmp, E);
  k_place<<<nBuck * PLS, 256, 0, stream>>>(tmp, off, cur, srow, N, E);

  // pack weights
  k_packbf<<<192, 256, 0, stream>>>(w1i, w1r, Bf);
  k_pack<<<(HD * 32 + 255) / 256, 256, 0, stream>>>(w2i, w2r, W2c, HD, 16);
  k_pack<<<(HD * 20 + 255) / 256, 256, 0, stream>>>(w3i, w3r, W3c, HD, 10);

  // layer 1 (bf16-split MFMA)
  k_gemm1<<<(N + 63) / 64, 256, 0, stream>>>(x, Bf, dinv, T, N);
  k_gather_relu<<<(N + 15) / 16, 256, 0, stream>>>(T, off, cnt, srow, dinv, b1, h, N);
  // layer 2
  k_gemm_small<<<(N * 32 + 255) / 256, 256, 0, stream>>>(h, W2c, dinv, T, N, 32, 16);
  k_gather_relu<<<(N + 15) / 16, 256, 0, stream>>>(T, off, cnt, srow, dinv, b2, h, N);
  // layer 3 + internal relu + log_softmax
  k_gemm_small<<<(N * 32 + 255) / 256, 256, 0, stream>>>(h, W3c, dinv, T, N, 20, 10);
  k_gather_lsm<<<(N + 15) / 16, 256, 0, stream>>>(T, off, cnt, srow, dinv, b3, out, N);
}

// Round 6
// 914.852 us; speedup vs baseline: 1.9517x; 1.0214x over previous
//
#include <hip/hip_runtime.h>
#include <hip/hip_bf16.h>
#include <cstdint>
#include <cstddef>

#define F_IN 767
#define HD   16

typedef __attribute__((ext_vector_type(8))) short short8v;   // 8 bf16 (4 VGPR) MFMA A/B frag
typedef __attribute__((ext_vector_type(4))) float float4v;   // MFMA C/D frag
typedef float __attribute__((ext_vector_type(4), aligned(4))) float4a;  // 4B-aligned vector load

static __device__ __forceinline__ unsigned short f2bf(float f) {
  unsigned int u = __float_as_uint(f);
  return (unsigned short)((u + 0x7fffu + ((u >> 16) & 1u)) >> 16);   // RNE
}
static __device__ __forceinline__ float bf2f(unsigned short b) {
  return __uint_as_float(((unsigned int)b) << 16);
}

// ======================= counting-sort of edges by col =======================

__global__ void k_hist(const int* __restrict__ col, int* __restrict__ cnt, int E) {
  int base = (blockIdx.x * 256 + threadIdx.x) * 4;
  if (base + 3 < E) {
    int4 v = *(const int4*)&col[base];
    atomicAdd(&cnt[v.x], 1);
    atomicAdd(&cnt[v.y], 1);
    atomicAdd(&cnt[v.z], 1);
    atomicAdd(&cnt[v.w], 1);
  } else {
    for (int e = base; e < E; ++e) atomicAdd(&cnt[col[e]], 1);
  }
}

// block scan: 256 threads x 4 items = 1024 items/block.
__global__ void k_scan1(const int* __restrict__ cnt, int* __restrict__ off,
                        int* __restrict__ bsum, int N) {
  __shared__ int lds[256];
  int t = threadIdx.x;
  int base = blockIdx.x * 1024 + t * 4;
  int4 v = make_int4(0, 0, 0, 0);
  if (base + 3 < N) {
    v = *(const int4*)&cnt[base];
  } else {
    if (base + 0 < N) v.x = cnt[base + 0];
    if (base + 1 < N) v.y = cnt[base + 1];
    if (base + 2 < N) v.z = cnt[base + 2];
    if (base + 3 < N) v.w = cnt[base + 3];
  }
  int s = v.x + v.y + v.z + v.w;
  lds[t] = s;
  __syncthreads();
  for (int d = 1; d < 256; d <<= 1) {
    int add = (t >= d) ? lds[t - d] : 0;
    __syncthreads();
    lds[t] += add;
    __syncthreads();
  }
  int excl = lds[t] - s;
  if (t == 255) bsum[blockIdx.x] = lds[255];
  int run = excl;
  if (base + 0 < N) off[base + 0] = run; run += v.x;
  if (base + 1 < N) off[base + 1] = run; run += v.y;
  if (base + 2 < N) off[base + 2] = run; run += v.z;
  if (base + 3 < N) off[base + 3] = run;
}

// single block: exclusive scan of block sums in place (nb <= 256)
__global__ void k_scan2(int* __restrict__ bsum, int nb) {
  __shared__ int lds[256];
  int t = threadIdx.x;
  int s = (t < nb) ? bsum[t] : 0;
  lds[t] = s;
  __syncthreads();
  for (int d = 1; d < 256; d <<= 1) {
    int add = (t >= d) ? lds[t - d] : 0;
    __syncthreads();
    lds[t] += add;
    __syncthreads();
  }
  if (t < nb) bsum[t] = lds[t] - s;
}

// finalize offsets, copy to cursor, compute dinv
__global__ void k_scan3(const int* __restrict__ cnt, int* __restrict__ off,
                        int* __restrict__ cur, float* __restrict__ dinv,
                        const int* __restrict__ bsum, int N) {
  int i = blockIdx.x * 256 + threadIdx.x;
  if (i < N) {
    int o = off[i] + bsum[i >> 10];
    off[i] = o;
    cur[i] = o;
    int c = cnt[i];
    dinv[i] = (c > 0) ? rsqrtf((float)c) : 0.f;
  }
}

// ======================= two-phase edge partition =======================
#define PSH     9
#define PA_TILE 4096

__global__ void k_binit(const int* __restrict__ off, int* __restrict__ bcur, int N, int E) {
  int b = threadIdx.x;
  int cb = b << PSH;
  bcur[b] = (cb < N) ? off[cb] : E;
}

__global__ __launch_bounds__(256) void k_part(const int* __restrict__ row,
                                              const int* __restrict__ col,
                                              int* __restrict__ bcur,
                                              int2* __restrict__ tmp, int E) {
  __shared__ int  hcnt[256];
  __shared__ int  hoff[256];
  __shared__ int  hcur[256];
  __shared__ int  gbase[256];
  __shared__ int2 st[PA_TILE];      // 32 KB
  int t = threadIdx.x;
  int tile = blockIdx.x * PA_TILE;
  int nE = min(PA_TILE, E - tile);

  hcnt[t] = 0;
  __syncthreads();

  int r[16], c[16];
  #pragma unroll
  for (int i = 0; i < 16; ++i) {
    int li = i * 256 + t;
    if (li < nE) {
      r[i] = row[tile + li];
      c[i] = col[tile + li];
      atomicAdd(&hcnt[c[i] >> PSH], 1);
    } else c[i] = -1;
  }
  __syncthreads();

  int s = hcnt[t];
  hoff[t] = s;
  __syncthreads();
  for (int d = 1; d < 256; d <<= 1) {
    int add = (t >= d) ? hoff[t - d] : 0;
    __syncthreads();
    hoff[t] += add;
    __syncthreads();
  }
  int excl = hoff[t] - s;
  hcur[t] = excl;
  gbase[t] = (s > 0) ? atomicAdd(&bcur[t], s) : 0;
  __syncthreads();

  #pragma unroll
  for (int i = 0; i < 16; ++i) {
    if (c[i] >= 0) {
      int p = atomicAdd(&hcur[c[i] >> PSH], 1);
      st[p] = make_int2(r[i], c[i]);
    }
  }
  __syncthreads();

  #pragma unroll
  for (int i = 0; i < 16; ++i) {
    int idx = i * 256 + t;
    if (idx < nE) {
      int2 v = st[idx];
      int b = v.y >> PSH;
      tmp[gbase[b] + (idx - (hoff[b] - hcnt[b]))] = v;
    }
  }
}

#define PLS 8
__global__ __launch_bounds__(256) void k_place(const int2* __restrict__ tmp,
                                               const int* __restrict__ off,
                                               int* __restrict__ cur,
                                               int* __restrict__ srow, int N, int E) {
  int b = blockIdx.x / PLS, sp = blockIdx.x % PLS;
  int cb = b << PSH;
  if (cb >= N) return;
  int start = off[cb];
  int nx = (b + 1) << PSH;
  int end = (nx < N) ? off[nx] : E;
  int len = end - start;
  int per = (len + PLS - 1) / PLS;
  int s0 = start + sp * per;
  int s1 = min(s0 + per, end);
  for (int e = s0 + threadIdx.x; e < s1; e += 256) {
    int2 v = tmp[e];
    int p = atomicAdd(&cur[v.y], 1);
    srow[p] = v.x;
  }
}

// ======================= weight packs =======================
// small-layer pack: W[16][32]: cols 0..15 <- wi (pad 0), cols 16..31 <- wr (pad 0)
__global__ void k_pack2(const float* __restrict__ wi, const float* __restrict__ wr,
                        float* __restrict__ Wc, int P) {
  int i = blockIdx.x * 256 + threadIdx.x;
  if (i < 16 * 32) {
    int k = i >> 5, c = i & 31;
    float v = 0.f;
    if (c < 16) { if (c < P) v = wi[k * P + c]; }
    else        { int cc = c - 16; if (cc < P) v = wr[k * P + cc]; }
    Wc[i] = v;
  }
}

// B-fragment pre-pack for MFMA GEMM1:
// Bf layout: [s(24)][term(2: hi,lo)][half(2)][lane(64)][elem(8)] bf16 bits.
// B[k][col]: col = half*16 + (lane&15); k = s*32 + (lane>>4)*8 + elem.
__global__ void k_packbf(const float* __restrict__ wi, const float* __restrict__ wr,
                         unsigned short* __restrict__ Bf) {
  int idx = blockIdx.x * 256 + threadIdx.x;
  if (idx >= 24 * 2 * 2 * 64 * 8) return;
  int j    = idx & 7;
  int l    = (idx >> 3) & 63;
  int half = (idx >> 9) & 1;
  int term = (idx >> 10) & 1;
  int s    = idx >> 11;
  int col  = half * 16 + (l & 15);
  int k    = s * 32 + (l >> 4) * 8 + j;
  float w = 0.f;
  if (k < F_IN) w = (col < 16) ? wi[k * 16 + col] : wr[k * 16 + (col - 16)];
  unsigned short hi = f2bf(w);
  unsigned short lo = f2bf(w - bf2f(hi));
  Bf[idx] = (term == 0) ? hi : lo;
}

// ======================= GEMM1 via bf16 MFMA, 3-term f32-split =======================
__global__ __launch_bounds__(256) void k_gemm1(const float* __restrict__ x,
                                               const unsigned short* __restrict__ Bf,
                                               const float* __restrict__ dinv,
                                               float* __restrict__ T, int N) {
  int t = threadIdx.x;
  int w = t >> 6, l = t & 63;
  int kg = l >> 4;                       // 0..3
  int rowA = blockIdx.x * 64 + w * 16 + (l & 15);
  const float* xr = x + (size_t)min(rowA, N - 1) * F_IN;
  const short8v* Bfv = (const short8v*)Bf;

  float4v c0 = {0.f, 0.f, 0.f, 0.f};
  float4v c1 = {0.f, 0.f, 0.f, 0.f};

  for (int s = 0; s < 24; ++s) {
    int kbase = s * 32 + kg * 8;
    float v[8];
    if (s < 23) {
      float4a a = *(const float4a*)(xr + kbase);
      float4a b = *(const float4a*)(xr + kbase + 4);
      v[0] = a.x; v[1] = a.y; v[2] = a.z; v[3] = a.w;
      v[4] = b.x; v[5] = b.y; v[6] = b.z; v[7] = b.w;
    } else {
      #pragma unroll
      for (int j = 0; j < 8; ++j) {
        int k = kbase + j;
        v[j] = (k < F_IN) ? xr[k] : 0.f;
      }
    }
    short8v ah, al;
    #pragma unroll
    for (int j = 0; j < 8; ++j) {
      unsigned short h = f2bf(v[j]);
      ah[j] = (short)h;
      al[j] = (short)f2bf(v[j] - bf2f(h));
    }
    short8v bh0 = Bfv[(s * 4 + 0) * 64 + l];
    short8v bh1 = Bfv[(s * 4 + 1) * 64 + l];
    short8v bl0 = Bfv[(s * 4 + 2) * 64 + l];
    short8v bl1 = Bfv[(s * 4 + 3) * 64 + l];
    c0 = __builtin_amdgcn_mfma_f32_16x16x32_bf16(ah, bh0, c0, 0, 0, 0);
    c1 = __builtin_amdgcn_mfma_f32_16x16x32_bf16(ah, bh1, c1, 0, 0, 0);
    c0 = __builtin_amdgcn_mfma_f32_16x16x32_bf16(al, bh0, c0, 0, 0, 0);
    c1 = __builtin_amdgcn_mfma_f32_16x16x32_bf16(al, bh1, c1, 0, 0, 0);
    c0 = __builtin_amdgcn_mfma_f32_16x16x32_bf16(ah, bl0, c0, 0, 0, 0);
    c1 = __builtin_amdgcn_mfma_f32_16x16x32_bf16(ah, bl1, c1, 0, 0, 0);
  }

  // C/D layout (HW-verified): col = lane&15, row = (lane>>4)*4 + reg
  int rowC = blockIdx.x * 64 + w * 16 + (l >> 4) * 4;
  int colC = l & 15;
  #pragma unroll
  for (int j = 0; j < 4; ++j) {
    int gr = rowC + j;
    if (gr < N) {
      float d = dinv[gr];
      T[(size_t)gr * 32 + colC]      = c0[j] * d;
      T[(size_t)gr * 32 + 16 + colC] = c1[j];
    }
  }
}

// ======================= fused gather + relu + next-layer 16x32 GEMM ===================
// Tin pitch 32: cols 0..15 = dinv[r]*init part, 16..31 = root part.
// h_j = relu(dinv[n]*acc_j + root_j + bias_j), lane j of each 16-lane group.
// Tout[n][c] = (h @ W)[c], cols 0..15 scaled by dinv[n].  W is [16][32] (zero-padded).
__global__ void k_gather_fuse(const float* __restrict__ Tin, const int* __restrict__ off,
                              const int* __restrict__ cnt, const int* __restrict__ srow,
                              const float* __restrict__ dinv, const float* __restrict__ bias,
                              const float* __restrict__ W,
                              float* __restrict__ Tout, int N) {
  int t = threadIdx.x;
  int j = t & 15, ln = t >> 4;
  int n = blockIdx.x * 16 + ln;
  if (n >= N) return;
  const float* Tj = Tin + j;
  int s = off[n], c = cnt[n];
  float acc = 0.f;
  int p = s, e8 = s + (c & ~7);
  for (; p < e8; p += 8) {
    int r0 = srow[p],     r1 = srow[p + 1], r2 = srow[p + 2], r3 = srow[p + 3];
    int r4 = srow[p + 4], r5 = srow[p + 5], r6 = srow[p + 6], r7 = srow[p + 7];
    float v0 = Tj[(size_t)r0 * 32], v1 = Tj[(size_t)r1 * 32];
    float v2 = Tj[(size_t)r2 * 32], v3 = Tj[(size_t)r3 * 32];
    float v4 = Tj[(size_t)r4 * 32], v5 = Tj[(size_t)r5 * 32];
    float v6 = Tj[(size_t)r6 * 32], v7 = Tj[(size_t)r7 * 32];
    acc += v0; acc += v1; acc += v2; acc += v3;
    acc += v4; acc += v5; acc += v6; acc += v7;
  }
  for (; p < s + c; ++p) acc += Tj[(size_t)srow[p] * 32];
  float d = dinv[n];
  float h = fmaxf(d * acc + Tin[(size_t)n * 32 + 16 + j] + bias[j], 0.f);
  // 16x32 GEMM via intra-group shuffle (k ascending: same FP order as before)
  float o0 = 0.f, o1 = 0.f;
  #pragma unroll
  for (int k = 0; k < 16; ++k) {
    float hk = __shfl(h, k, 16);
    o0 += hk * W[k * 32 + j];
    o1 += hk * W[k * 32 + 16 + j];
  }
  Tout[(size_t)n * 32 + j]      = o0 * d;
  Tout[(size_t)n * 32 + 16 + j] = o1;
}

// ======================= gather + relu + log_softmax (layer 3, pitch 32) ===========
// ARMAConv applies relu INTERNALLY in every conv, including conv3.
__global__ void k_gather_lsm(const float* __restrict__ Tin, const int* __restrict__ off,
                             const int* __restrict__ cnt, const int* __restrict__ srow,
                             const float* __restrict__ dinv, const float* __restrict__ b3,
                             float* __restrict__ out, int N) {
  int t = threadIdx.x;
  int j = t & 15, ln = t >> 4;
  int n = blockIdx.x * 16 + ln;
  bool act = (n < N) && (j < 10);
  float v = -1e30f;
  if (act) {
    const float* Tj = Tin + j;
    int s = off[n], c = cnt[n];
    float acc = 0.f;
    int p = s, e8 = s + (c & ~7);
    for (; p < e8; p += 8) {
      int r0 = srow[p],     r1 = srow[p + 1], r2 = srow[p + 2], r3 = srow[p + 3];
      int r4 = srow[p + 4], r5 = srow[p + 5], r6 = srow[p + 6], r7 = srow[p + 7];
      float v0 = Tj[(size_t)r0 * 32], v1 = Tj[(size_t)r1 * 32];
      float v2 = Tj[(size_t)r2 * 32], v3 = Tj[(size_t)r3 * 32];
      float v4 = Tj[(size_t)r4 * 32], v5 = Tj[(size_t)r5 * 32];
      float v6 = Tj[(size_t)r6 * 32], v7 = Tj[(size_t)r7 * 32];
      acc += v0; acc += v1; acc += v2; acc += v3;
      acc += v4; acc += v5; acc += v6; acc += v7;
    }
    for (; p < s + c; ++p) acc += Tj[(size_t)srow[p] * 32];
    v = dinv[n] * acc + Tin[(size_t)n * 32 + 16 + j] + b3[j];
    v = fmaxf(v, 0.f);   // ARMAConv internal relu on conv3 output
  }
  float m = v;
  #pragma unroll
  for (int mask = 8; mask >= 1; mask >>= 1) m = fmaxf(m, __shfl_xor(m, mask, 16));
  float e = act ? __expf(v - m) : 0.f;
  float sum = e;
  #pragma unroll
  for (int mask = 8; mask >= 1; mask >>= 1) sum += __shfl_xor(sum, mask, 16);
  if (act) out[(size_t)n * 10 + j] = (v - m) - __logf(sum);
}

// ======================= launch =======================
extern "C" void kernel_launch(void* const* d_in, const int* in_sizes, int n_in,
                              void* d_out, int out_size, void* d_ws, size_t ws_size,
                              hipStream_t stream) {
  const float* x    = (const float*)d_in[0];
  const int* eidx   = (const int*)d_in[1];
  const float* w1i  = (const float*)d_in[2];
  const float* w1r  = (const float*)d_in[3];
  const float* b1   = (const float*)d_in[4];
  const float* w2i  = (const float*)d_in[5];
  const float* w2r  = (const float*)d_in[6];
  const float* b2   = (const float*)d_in[7];
  const float* w3i  = (const float*)d_in[8];
  const float* w3r  = (const float*)d_in[9];
  const float* b3   = (const float*)d_in[10];
  float* out = (float*)d_out;

  const int N = in_sizes[0] / F_IN;     // 100000
  const int E = in_sizes[1] / 2;        // 3200000
  const int* row = eidx;
  const int* col = eidx + E;

  // workspace carve-up (256B aligned)
  char* p = (char*)d_ws;
  auto alloc = [&](size_t bytes) { void* r = (void*)p; p += (bytes + 255) & ~(size_t)255; return r; };
  int*   cnt  = (int*)alloc((size_t)N * 4);
  int*   off  = (int*)alloc((size_t)N * 4);
  int*   cur  = (int*)alloc((size_t)N * 4);
  float* dinv = (float*)alloc((size_t)N * 4);
  int*   bsum = (int*)alloc(1024);
  int*   bcur = (int*)alloc(1024);
  unsigned short* Bf = (unsigned short*)alloc((size_t)24 * 2 * 2 * 64 * 8 * 2);   // 96 KB
  float* W2c  = (float*)alloc((size_t)16 * 32 * 4);
  float* W3c  = (float*)alloc((size_t)16 * 32 * 4);
  int*   srow = (int*)alloc((size_t)E * 4);
  // big (E*8 = 25.6MB): tmp aliases T1(12.8MB)+T2(12.8MB); tmp fully consumed by
  // k_place before gemm1 first writes T1.  T3 reuses T1 (dead after gather1).
  char*  big  = (char*)alloc((size_t)E * 8);
  int2*  tmp  = (int2*)big;
  float* T1   = (float*)big;
  float* T2   = (float*)(big + (size_t)N * 32 * 4);
  float* T3   = T1;

  const int nbScan = (N + 1023) / 1024;     // 98
  const int nBuck = (N + (1 << PSH) - 1) >> PSH;   // 196

  // edge sort (counting sort by col, two-phase bucket partition) + dinv
  hipMemsetAsync(cnt, 0, (size_t)N * 4, stream);
  k_hist <<<(E / 4 + 255) / 256, 256, 0, stream>>>(col, cnt, E);
  k_scan1<<<nbScan, 256, 0, stream>>>(cnt, off, bsum, N);
  k_scan2<<<1, 256, 0, stream>>>(bsum, nbScan);
  k_scan3<<<(N + 255) / 256, 256, 0, stream>>>(cnt, off, cur, dinv, bsum, N);
  k_binit<<<1, 256, 0, stream>>>(off, bcur, N, E);
  k_part <<<(E + PA_TILE - 1) / PA_TILE, 256, 0, stream>>>(row, col, bcur, tmp, E);
  k_place<<<nBuck * PLS, 256, 0, stream>>>(tmp, off, cur, srow, N, E);

  // pack weights
  k_packbf<<<192, 256, 0, stream>>>(w1i, w1r, Bf);
  k_pack2<<<2, 256, 0, stream>>>(w2i, w2r, W2c, 16);
  k_pack2<<<2, 256, 0, stream>>>(w3i, w3r, W3c, 10);

  // layer 1 (bf16-split MFMA) -> T1
  k_gemm1<<<(N + 63) / 64, 256, 0, stream>>>(x, Bf, dinv, T1, N);
  // gather1 + relu + (h @ W2) -> T2
  k_gather_fuse<<<(N + 15) / 16, 256, 0, stream>>>(T1, off, cnt, srow, dinv, b1, W2c, T2, N);
  // gather2 + relu + (h @ W3) -> T3
  k_gather_fuse<<<(N + 15) / 16, 256, 0, stream>>>(T2, off, cnt, srow, dinv, b2, W3c, T3, N);
  // gather3 + internal relu + log_softmax
  k_gather_lsm<<<(N + 15) / 16, 256, 0, stream>>>(T3, off, cnt, srow, dinv, b3, out, N);
}